// Round 9
// baseline (401.771 us; speedup 1.0000x reference)
//
#include <hip/hip_runtime.h>
#include <math.h>

#define DMODEL 768
#define NHEAD 12
#define DKDIM 64
#define BB 2
#define SS 2048
#define MROWS (BB * SS)    // 4096
#define WELEM (DMODEL * DMODEL)  // 589824

typedef unsigned short bf16_t;
typedef __attribute__((ext_vector_type(8))) short s8;   // 8 bf16 = 4 VGPRs (MFMA A/B frag)
typedef __attribute__((ext_vector_type(4))) float f4;   // MFMA C/D frag

#define MFMA(a, b, c) __builtin_amdgcn_mfma_f32_16x16x32_bf16((a), (b), (c), 0, 0, 0)

__device__ __forceinline__ bf16_t f2bf(float f) {   // round-to-nearest-even
    unsigned u = __float_as_uint(f);
    u += 0x7fffu + ((u >> 16) & 1u);
    return (bf16_t)(u >> 16);
}
__device__ __forceinline__ unsigned pack2(float a, float b) {
    return (unsigned)f2bf(a) | ((unsigned)f2bf(b) << 16);
}
__device__ __forceinline__ s8 ldfrag(const bf16_t* p) {
    union { uint4 u; s8 s; } x;
    x.u = *(const uint4*)p;
    return x.s;
}

// stage 16 consecutive elements -> 2 x uint4 of packed bf16
__device__ __forceinline__ void ld_stage(const bf16_t* p, uint4& u0, uint4& u1) {
    u0 = *(const uint4*)p;
    u1 = *(const uint4*)(p + 8);
}
__device__ __forceinline__ void ld_stage(const float* p, uint4& u0, uint4& u1) {
    const float4 f0 = *(const float4*)p;
    const float4 f1 = *(const float4*)(p + 4);
    const float4 f2 = *(const float4*)(p + 8);
    const float4 f3 = *(const float4*)(p + 12);
    u0.x = pack2(f0.x, f0.y); u0.y = pack2(f0.z, f0.w);
    u0.z = pack2(f1.x, f1.y); u0.w = pack2(f1.z, f1.w);
    u1.x = pack2(f2.x, f2.y); u1.y = pack2(f2.z, f2.w);
    u1.z = pack2(f3.x, f3.y); u1.w = pack2(f3.z, f3.w);
}

// ---------------------------------------------------------------------------
// Weight prepass: fp32 -> bf16, 4 matrices of 768x768. grid (576, 4), 256 thr.
// ---------------------------------------------------------------------------
__global__ void cvt_weights(const float* __restrict__ W0, const float* __restrict__ W1,
                            const float* __restrict__ W2, const float* __restrict__ W3,
                            bf16_t* __restrict__ dst)
{
    const float* src = (blockIdx.y == 0) ? W0 : (blockIdx.y == 1) ? W1
                     : (blockIdx.y == 2) ? W2 : W3;
    bf16_t* d = dst + (size_t)blockIdx.y * WELEM;
    const int i = (blockIdx.x * 256 + threadIdx.x) * 4;
    const float4 v = *(const float4*)(src + i);
    ushort4 h;
    h.x = f2bf(v.x); h.y = f2bf(v.y); h.z = f2bf(v.z); h.w = f2bf(v.w);
    *(ushort4*)(d + i) = h;
}

// ---------------------------------------------------------------------------
// LDS-staged MFMA GEMM (m93-style): C[M,768] = A[M,768] @ W[768,768]^T + bias.
// 128x128 block tile, BK=32, 256 thr = 4 waves in 2x2. Unchanged from round 8.
// ---------------------------------------------------------------------------
template<typename TA, typename TO>
__global__ __launch_bounds__(256) void gemm_tiled(
    const TA* __restrict__ A0, const TA* __restrict__ A1, const TA* __restrict__ A2,
    const bf16_t* __restrict__ W0, const bf16_t* __restrict__ W1, const bf16_t* __restrict__ W2,
    const float* __restrict__ bias0, const float* __restrict__ bias1, const float* __restrict__ bias2,
    TO* __restrict__ C0, TO* __restrict__ C1, TO* __restrict__ C2)
{
    __shared__ uint4 As4[128 * 4];   // 128 rows x 4 swizzled 16B blocks (8 KB)
    __shared__ uint4 Bs4[128 * 4];

    const int z = blockIdx.z;
    const TA*     A    = (z == 0) ? A0 : (z == 1) ? A1 : A2;
    const bf16_t* W    = (z == 0) ? W0 : (z == 1) ? W1 : W2;
    const float*  bias = (z == 0) ? bias0 : (z == 1) ? bias1 : bias2;
    TO*           C    = (z == 0) ? C0 : (z == 1) ? C1 : C2;

    const int tid  = threadIdx.x;
    const int lane = tid & 63;
    const int w    = tid >> 6;
    const int wm   = w & 1;
    const int wn   = w >> 1;
    const int l15  = lane & 15;
    const int quad = lane >> 4;
    const int m0   = blockIdx.y * 128;
    const int n0   = blockIdx.x * 128;

    const int srow  = tid >> 1;
    const int shalf = tid & 1;
    const int sw    = srow & 3;

    const TA*     aptr = A + (size_t)(m0 + srow) * DMODEL + shalf * 16;
    const bf16_t* wptr = W + (size_t)(n0 + srow) * DMODEL + shalf * 16;

    f4 acc[4][4];
    #pragma unroll
    for (int i = 0; i < 4; i++)
        #pragma unroll
        for (int j = 0; j < 4; j++)
            acc[i][j] = (f4){0.f, 0.f, 0.f, 0.f};

    for (int k0 = 0; k0 < DMODEL; k0 += 32) {
        uint4 au0, au1, bu0, bu1;
        ld_stage(aptr + k0, au0, au1);
        ld_stage(wptr + k0, bu0, bu1);
        __syncthreads();
        As4[srow * 4 + ((shalf * 2 + 0) ^ sw)] = au0;
        As4[srow * 4 + ((shalf * 2 + 1) ^ sw)] = au1;
        Bs4[srow * 4 + ((shalf * 2 + 0) ^ sw)] = bu0;
        Bs4[srow * 4 + ((shalf * 2 + 1) ^ sw)] = bu1;
        __syncthreads();

        s8 af[4], bf[4];
        #pragma unroll
        for (int t = 0; t < 4; t++) {
            const int ar = wm * 64 + t * 16 + l15;
            const int br = wn * 64 + t * 16 + l15;
            union { uint4 u; s8 s; } xa, xb;
            xa.u = As4[ar * 4 + (quad ^ (ar & 3))];
            xb.u = Bs4[br * 4 + (quad ^ (br & 3))];
            af[t] = xa.s;
            bf[t] = xb.s;
        }
        #pragma unroll
        for (int mt = 0; mt < 4; mt++)
            #pragma unroll
            for (int nt = 0; nt < 4; nt++)
                acc[mt][nt] = MFMA(af[mt], bf[nt], acc[mt][nt]);
    }

    #pragma unroll
    for (int mt = 0; mt < 4; mt++) {
        #pragma unroll
        for (int nt = 0; nt < 4; nt++) {
            const int col = n0 + wn * 64 + nt * 16 + l15;
            const float bb = bias[col];
            #pragma unroll
            for (int reg = 0; reg < 4; reg++) {
                const int row = m0 + wm * 64 + mt * 16 + quad * 4 + reg;
                const float val = acc[mt][nt][reg] + bb;
                TO* dst = C + (size_t)row * DMODEL + col;
                if constexpr (sizeof(TO) == 2) *dst = f2bf(val);
                else                           *dst = val;
            }
        }
    }
}

// ---------------------------------------------------------------------------
// MFMA flash attention — BARRIER-FREE. Each wave owns 16 Q rows AND its own
// private V-tile LDS region (Vs[w]) and P region (Ps[w]); all LDS traffic is
// wave-local (same-wave DS ops are in-order), so no __syncthreads at all.
// 1-deep software prefetch of next K-frags / V-stage regs / mask words
// overlaps global latency with the softmax VALU chain.
// LDS: Vs 36.9 KB + Ps 9.2 KB = 46 KB -> 3 blocks/CU (= grid supply).
// grid (S/64, H, B).
// ---------------------------------------------------------------------------
__global__ __launch_bounds__(256, 3) void attn_mfma(
    const bf16_t* __restrict__ Q, const bf16_t* __restrict__ K,
    const bf16_t* __restrict__ V, const int* __restrict__ mask,
    bf16_t* __restrict__ O)
{
    __shared__ unsigned Vs[4][64][36];    // per-wave V^T tile (packed k-pairs)
    __shared__ unsigned Ps[4][16][36];    // per-wave P, A-layout packed pairs

    const int tid  = threadIdx.x;
    const int lane = tid & 63;
    const int w    = tid >> 6;
    const int l15  = lane & 15;
    const int quad = lane >> 4;
    const int q0   = blockIdx.x * 64;
    const int h    = blockIdx.y;
    const int b    = blockIdx.z;
    const size_t base = ((size_t)b * SS) * DMODEL + (size_t)h * DKDIM;

    const bf16_t* qrow = Q + base + (size_t)(q0 + w * 16 + l15) * DMODEL + quad * 8;
    const s8 qf0 = ldfrag(qrow);
    const s8 qf1 = ldfrag(qrow + 32);

    f4 oacc[4];
    float m_run[4], l_run[4];
    #pragma unroll
    for (int i = 0; i < 4; i++) {
        oacc[i] = (f4){0.f, 0.f, 0.f, 0.f};
        m_run[i] = -3.0e30f; l_run[i] = 0.0f;
    }

    const int kp   = lane & 31;   // V staging k-pair
    const int half = lane >> 5;   // V staging d-half

    const int* mrow = mask + (size_t)b * SS * SS + (size_t)(q0 + w * 16 + quad * 4) * SS;

    // prefetch state (tile k0): K frags, V staging regs, mask words
    s8   kf[4][2];
    uint4 vreg[4][2];
    int  mk[4][4];

    auto prefetch = [&](int kc) {
        #pragma unroll
        for (int nt = 0; nt < 4; nt++) {
            const bf16_t* krow = K + base + (size_t)(kc + nt * 16 + l15) * DMODEL + quad * 8;
            kf[nt][0] = ldfrag(krow);
            kf[nt][1] = ldfrag(krow + 32);
        }
        #pragma unroll
        for (int c = 0; c < 4; c++) {
            const int oct = half * 4 + c;
            const bf16_t* vrow = V + base + (size_t)(kc + 2 * kp) * DMODEL + oct * 8;
            vreg[c][0] = *(const uint4*)vrow;
            vreg[c][1] = *(const uint4*)(vrow + DMODEL);
        }
        #pragma unroll
        for (int reg = 0; reg < 4; reg++)
            #pragma unroll
            for (int nt = 0; nt < 4; nt++)
                mk[reg][nt] = mrow[(size_t)reg * SS + kc + nt * 16 + l15];
    };

    prefetch(0);

    for (int k0 = 0; k0 < SS; k0 += 64) {
        // 1. stage V tile (wave-private) from prefetched regs
        #pragma unroll
        for (int c = 0; c < 4; c++) {
            const int oct = half * 4 + c;
            const unsigned short* pa = (const unsigned short*)&vreg[c][0];
            const unsigned short* pb = (const unsigned short*)&vreg[c][1];
            #pragma unroll
            for (int i = 0; i < 8; i++)
                Vs[w][oct * 8 + i][kp] = (unsigned)pa[i] | ((unsigned)pb[i] << 16);
        }

        // 2. S = Q K^T from prefetched K frags
        f4 sacc[4];
        #pragma unroll
        for (int nt = 0; nt < 4; nt++) {
            f4 zz = {0.f, 0.f, 0.f, 0.f};
            zz = MFMA(qf0, kf[nt][0], zz);
            zz = MFMA(qf1, kf[nt][1], zz);
            sacc[nt] = zz;
        }

        // 3. mask + online softmax (prefetched mask words)
        float p[4][4];
        #pragma unroll
        for (int reg = 0; reg < 4; reg++) {
            float sv[4];
            #pragma unroll
            for (int nt = 0; nt < 4; nt++)
                sv[nt] = mk[reg][nt] ? sacc[nt][reg] * 0.125f : -1.0e9f;

            float mx = fmaxf(fmaxf(sv[0], sv[1]), fmaxf(sv[2], sv[3]));
            mx = fmaxf(mx, __shfl_xor(mx, 1, 16));
            mx = fmaxf(mx, __shfl_xor(mx, 2, 16));
            mx = fmaxf(mx, __shfl_xor(mx, 4, 16));
            mx = fmaxf(mx, __shfl_xor(mx, 8, 16));

            const float m_new = fmaxf(m_run[reg], mx);
            const float alpha = __expf(m_run[reg] - m_new);
            float rs = 0.f;
            #pragma unroll
            for (int nt = 0; nt < 4; nt++) {
                p[reg][nt] = __expf(sv[nt] - m_new);
                rs += p[reg][nt];
            }
            rs += __shfl_xor(rs, 1, 16);
            rs += __shfl_xor(rs, 2, 16);
            rs += __shfl_xor(rs, 4, 16);
            rs += __shfl_xor(rs, 8, 16);

            l_run[reg] = l_run[reg] * alpha + rs;
            m_run[reg] = m_new;
            #pragma unroll
            for (int dt = 0; dt < 4; dt++) oacc[dt][reg] *= alpha;
        }

        // 4. issue next tile's prefetch (overlaps with steps 5)
        prefetch((k0 + 64) & (SS - 1));

        // 5. P -> Ps[w] (A-layout), then O += P @ V (all wave-local LDS)
        #pragma unroll
        for (int reg = 0; reg < 4; reg++) {
            #pragma unroll
            for (int nt = 0; nt < 4; nt++) {
                const float mine  = p[reg][nt];
                const float other = __shfl_xor(mine, 1, 16);
                if ((lane & 1) == 0)
                    Ps[w][quad * 4 + reg][nt * 8 + (l15 >> 1)] = pack2(mine, other);
            }
        }

        #pragma unroll
        for (int kt = 0; kt < 2; kt++) {
            union { uint4 u; s8 s; } pf;
            pf.u = *(const uint4*)&Ps[w][l15][kt * 16 + quad * 4];
            #pragma unroll
            for (int dt = 0; dt < 4; dt++) {
                union { uint4 u; s8 s; } vf;
                vf.u = *(const uint4*)&Vs[w][dt * 16 + l15][kt * 16 + quad * 4];
                oacc[dt] = MFMA(pf.s, vf.s, oacc[dt]);
            }
        }
    }

    #pragma unroll
    for (int reg = 0; reg < 4; reg++) {
        const float inv = 1.0f / l_run[reg];
        #pragma unroll
        for (int dt = 0; dt < 4; dt++) {
            O[base + (size_t)(q0 + w * 16 + quad * 4 + reg) * DMODEL + dt * 16 + l15] =
                f2bf(oacc[dt][reg] * inv);
        }
    }
}

// ---------------------------------------------------------------------------
extern "C" void kernel_launch(void* const* d_in, const int* in_sizes, int n_in,
                              void* d_out, int out_size, void* d_ws, size_t ws_size,
                              hipStream_t stream)
{
    const float* q    = (const float*)d_in[0];
    const float* k    = (const float*)d_in[1];
    const float* v    = (const float*)d_in[2];
    const int*   mask = (const int*)  d_in[3];
    const float* Wq   = (const float*)d_in[4];
    const float* bq   = (const float*)d_in[5];
    const float* Wk   = (const float*)d_in[6];
    const float* bk   = (const float*)d_in[7];
    const float* Wv   = (const float*)d_in[8];
    const float* bv   = (const float*)d_in[9];
    const float* Wo   = (const float*)d_in[10];
    const float* bo   = (const float*)d_in[11];
    float* out = (float*)d_out;

    // ws: 4 bf16 planes [4096x768] (25.2 MB) + 4 bf16 weight mats (4.5 MB)
    bf16_t* wsb = (bf16_t*)d_ws;
    const size_t plane = (size_t)MROWS * DMODEL;   // 3,145,728
    bf16_t* Qp  = wsb;
    bf16_t* Kp  = wsb + plane;
    bf16_t* Vp  = wsb + 2 * plane;
    bf16_t* Ctx = wsb + 3 * plane;
    bf16_t* Wqb = wsb + 4 * plane;
    bf16_t* Wkb = Wqb + WELEM;
    bf16_t* Wvb = Wkb + WELEM;
    bf16_t* Wob = Wvb + WELEM;

    cvt_weights<<<dim3(WELEM / 1024, 4), 256, 0, stream>>>(Wq, Wk, Wv, Wo, Wqb);

    // fused Q/K/V projections: grid (6, 32, 3)
    gemm_tiled<float, bf16_t><<<dim3(DMODEL / 128, MROWS / 128, 3), 256, 0, stream>>>(
        q, k, v, Wqb, Wkb, Wvb, bq, bk, bv, Qp, Kp, Vp);

    attn_mfma<<<dim3(SS / 64, NHEAD, BB), 256, 0, stream>>>(Qp, Kp, Vp, mask, Ctx);

    // output projection: grid (6, 32, 1)
    gemm_tiled<bf16_t, float><<<dim3(DMODEL / 128, MROWS / 128, 1), 256, 0, stream>>>(
        Ctx, Ctx, Ctx, Wob, Wob, Wob, bo, bo, bo, out, out, out);
}